// Round 1
// baseline (472.672 us; speedup 1.0000x reference)
//
#include <hip/hip_runtime.h>
#include <math.h>

// Problem constants (match reference)
#define Bg 16
#define Nn 2048
#define Ee (1<<20)
#define NT (Bg*Nn)
#define INC 256
#define DIMd 128
#define OUTC 6
#define ENCH 100
#define NATOMS 20

__device__ __forceinline__ float gelu_f(float x){
    return 0.5f*x*(1.0f+erff(x*0.70710678118654752440f));
}

// ---------------- Kernel 1: BatchNorm statistics (sum, sumsq per channel) ----
__global__ __launch_bounds__(256) void bn_stats_k(const float* __restrict__ x,
                                                  float* __restrict__ stats){
    int c = threadIdx.x;                 // channel
    int r0 = blockIdx.x * 128;           // 256 blocks x 128 rows = 32768
    const float* p = x + (size_t)r0*INC + c;
    float s = 0.f, s2 = 0.f;
    #pragma unroll 8
    for(int r=0;r<128;r++){ float v = p[(size_t)r*INC]; s += v; s2 += v*v; }
    atomicAdd(&stats[c], s);
    atomicAdd(&stats[INC+c], s2);
}

// ---------------- Kernel 2a: h1 = gelu(BN(x) @ W1 + b1)  [32768,256]x[256,256]
__global__ __launch_bounds__(256) void gemm1_k(const float* __restrict__ x,
        const float* __restrict__ stats, const float* __restrict__ gamma,
        const float* __restrict__ beta, const float* __restrict__ W1,
        const float* __restrict__ b1, float* __restrict__ h1){
    __shared__ float sc[INC], sh[INC];
    __shared__ float sA[64][36];   // pad 36: 16B-aligned rows, <=2-way banks
    __shared__ float sB[32][64];
    int tid = threadIdx.x;
    {   // per-channel scale/shift from global sums (cheap, redundant per block)
        float mu  = stats[tid]*(1.0f/NT);
        float var = stats[INC+tid]*(1.0f/NT) - mu*mu;
        float s = gamma[tid]/sqrtf(var + 1e-5f);
        sc[tid] = s; sh[tid] = beta[tid] - mu*s;
    }
    __syncthreads();
    int mb = blockIdx.x>>2, nb = blockIdx.x&3;     // 512 x 4 blocks
    int row0 = mb*64, n0 = nb*64;
    int tx = tid&15, ty = tid>>4;                  // 16x16 threads, 4x4 microtile
    float acc[4][4] = {};
    for(int k0=0;k0<INC;k0+=32){
        #pragma unroll
        for(int i=0;i<2;i++){                      // A tile 64x32, BN applied
            int l = tid + i*256;
            int r = l>>3, kq = (l&7)*4;
            float4 vx = *(const float4*)&x[(size_t)(row0+r)*INC + k0+kq];
            int k = k0+kq;
            sA[r][kq+0]=vx.x*sc[k+0]+sh[k+0];
            sA[r][kq+1]=vx.y*sc[k+1]+sh[k+1];
            sA[r][kq+2]=vx.z*sc[k+2]+sh[k+2];
            sA[r][kq+3]=vx.w*sc[k+3]+sh[k+3];
        }
        #pragma unroll
        for(int i=0;i<2;i++){                      // B tile 32x64
            int l = tid + i*256;
            int k = l>>4, c4 = (l&15)*4;
            *(float4*)&sB[k][c4] = *(const float4*)&W1[(size_t)(k0+k)*INC + n0 + c4];
        }
        __syncthreads();
        #pragma unroll
        for(int kk=0;kk<32;kk+=4){
            float ar[4][4];
            #pragma unroll
            for(int r=0;r<4;r++) *(float4*)&ar[r][0] = *(const float4*)&sA[ty*4+r][kk];
            #pragma unroll
            for(int u=0;u<4;u++){
                float4 b = *(const float4*)&sB[kk+u][tx*4];
                #pragma unroll
                for(int r=0;r<4;r++){
                    float a = ar[r][u];
                    acc[r][0]+=a*b.x; acc[r][1]+=a*b.y;
                    acc[r][2]+=a*b.z; acc[r][3]+=a*b.w;
                }
            }
        }
        __syncthreads();
    }
    float4 bv = *(const float4*)&b1[n0+tx*4];
    #pragma unroll
    for(int r=0;r<4;r++){
        float4 o;
        o.x = gelu_f(acc[r][0]+bv.x);
        o.y = gelu_f(acc[r][1]+bv.y);
        o.z = gelu_f(acc[r][2]+bv.z);
        o.w = gelu_f(acc[r][3]+bv.w);
        *(float4*)&h1[(size_t)(row0+ty*4+r)*INC + n0+tx*4] = o;
    }
}

// ------- Kernel 2b: h2 = gelu(h1@W2+b2); logits = h2@W3+b3; ids = argmax ----
__global__ __launch_bounds__(256) void gemm23_k(const float* __restrict__ h1,
     const float* __restrict__ W2, const float* __restrict__ b2,
     const float* __restrict__ W3, const float* __restrict__ b3,
     int* __restrict__ ids){
    __shared__ float sA[64][36];
    __shared__ float sB[32][128];   // W2 k-tile; reused for W3 [128][20]
    __shared__ float h2s[64][132];
    __shared__ float lgs[64][20];
    int tid = threadIdx.x;
    int row0 = blockIdx.x*64;       // 512 blocks
    int tx = tid&15, ty = tid>>4;   // 4 rows x 8 cols (split 4+4) per thread
    float acc[4][8] = {};
    for(int k0=0;k0<256;k0+=32){
        #pragma unroll
        for(int i=0;i<2;i++){
            int l = tid + i*256; int r = l>>3, kq = (l&7)*4;
            *(float4*)&sA[r][kq] = *(const float4*)&h1[(size_t)(row0+r)*256 + k0+kq];
        }
        #pragma unroll
        for(int i=0;i<4;i++){
            int l = tid + i*256; int k = l>>5, c4 = (l&31)*4;
            *(float4*)&sB[k][c4] = *(const float4*)&W2[(size_t)(k0+k)*128 + c4];
        }
        __syncthreads();
        #pragma unroll
        for(int kk=0;kk<32;kk+=4){
            float ar[4][4];
            #pragma unroll
            for(int r=0;r<4;r++) *(float4*)&ar[r][0] = *(const float4*)&sA[ty*4+r][kk];
            #pragma unroll
            for(int u=0;u<4;u++){
                float4 b0 = *(const float4*)&sB[kk+u][tx*4];
                float4 bq = *(const float4*)&sB[kk+u][64+tx*4];
                #pragma unroll
                for(int r=0;r<4;r++){
                    float a = ar[r][u];
                    acc[r][0]+=a*b0.x; acc[r][1]+=a*b0.y; acc[r][2]+=a*b0.z; acc[r][3]+=a*b0.w;
                    acc[r][4]+=a*bq.x; acc[r][5]+=a*bq.y; acc[r][6]+=a*bq.z; acc[r][7]+=a*bq.w;
                }
            }
        }
        __syncthreads();
    }
    float4 c0 = *(const float4*)&b2[tx*4];
    float4 c1 = *(const float4*)&b2[64+tx*4];
    #pragma unroll
    for(int r=0;r<4;r++){
        int row = ty*4+r;
        h2s[row][tx*4+0]    = gelu_f(acc[r][0]+c0.x);
        h2s[row][tx*4+1]    = gelu_f(acc[r][1]+c0.y);
        h2s[row][tx*4+2]    = gelu_f(acc[r][2]+c0.z);
        h2s[row][tx*4+3]    = gelu_f(acc[r][3]+c0.w);
        h2s[row][64+tx*4+0] = gelu_f(acc[r][4]+c1.x);
        h2s[row][64+tx*4+1] = gelu_f(acc[r][5]+c1.y);
        h2s[row][64+tx*4+2] = gelu_f(acc[r][6]+c1.z);
        h2s[row][64+tx*4+3] = gelu_f(acc[r][7]+c1.w);
    }
    float* w3s = (float*)sB;                       // reuse (W2 tile done)
    for(int l=tid;l<128*20;l+=256) w3s[l] = W3[l];
    __syncthreads();
    int n = tid>>2, q = tid&3;                     // 64 nodes x 4 col-groups
    float lg[5] = {};
    #pragma unroll 4
    for(int k=0;k<128;k++){
        float h = h2s[n][k];
        #pragma unroll
        for(int a=0;a<5;a++) lg[a] += h*w3s[k*20 + q*5 + a];
    }
    #pragma unroll
    for(int a=0;a<5;a++) lgs[n][q*5+a] = lg[a] + b3[q*5+a];
    __syncthreads();
    if(tid<64){                                    // numpy argmax: first max wins
        float best = lgs[tid][0]; int bi = 0;
        #pragma unroll
        for(int a=1;a<20;a++){ float v2 = lgs[tid][a]; if(v2>best){best=v2;bi=a;} }
        ids[row0+tid] = bi;
    }
}

// ---------------- Kernel 3: edge list -> dedup adjacency bitmask -------------
__global__ __launch_bounds__(256) void build_adj_k(const int* __restrict__ ei,
                                                   unsigned* __restrict__ mask){
    int e = blockIdx.x*256 + threadIdx.x;          // 4096 blocks, e < 2^20
    int s = ei[e], d = ei[Ee+e];
    if((s>>11) == (d>>11)){                        // intra-graph only (N=2048)
        int ld = d & (Nn-1);
        atomicOr(&mask[(size_t)s*64 + (ld>>5)], 1u<<(ld&31));
    }
}

// -------- Kernel 4: aggregation (bitmask histogram) + message GEMM + heads ---
__global__ __launch_bounds__(256) void msg_out_k(
    const int* __restrict__ ids, const unsigned* __restrict__ mask,
    const float* __restrict__ embed, const float* __restrict__ W_msg,
    const float* __restrict__ b_msg, const float* __restrict__ w_coor,
    const float* __restrict__ A1, const float* __restrict__ a1v,
    const float* __restrict__ A2, const float* __restrict__ a2v,
    const float* __restrict__ dalpha, const float* __restrict__ dw,
    const float* __restrict__ db, const float* __restrict__ coords,
    float* __restrict__ out_ang, float* __restrict__ out_z,
    float* __restrict__ out_co)
{
    __shared__ float v[32][136];    // v = h+m; later hout (pad 136: aligned f4)
    __shared__ float wt[32][136];   // W_msg k-tile; later t1 [32][100]
    __shared__ __align__(16) unsigned char arena[22784]; // sid+emb+hist | a1t
    __shared__ float s_bm[128];
    __shared__ float s_wc[384];
    __shared__ float s_A2[600];
    __shared__ float s_a1[100];
    __shared__ float s_a2[8];
    __shared__ float s_dyt[16];     // [0]=alpha, [1..6]=w, [8..13]=b

    unsigned char* sid   = arena;                                   // 2048 B
    float*         emb   = (float*)(arena + 2048);                  // 10240 B
    unsigned short* hist = (unsigned short*)(arena + 2048 + 10240); // 10240 B
    float*         a1t   = (float*)arena;                           // phase C

    int tid = threadIdx.x;
    int g = blockIdx.x>>6, tile = blockIdx.x&63;   // 16 graphs x 64 tiles
    int gn0 = g*Nn + tile*32;

    // --- cooperative loads -------------------------------------------------
    for(int l=tid;l<NATOMS*128;l+=256) emb[l] = embed[l];
    #pragma unroll
    for(int i=0;i<8;i++){ int j = tid + i*256; sid[j] = (unsigned char)ids[g*Nn + j]; }
    if(tid<128) s_bm[tid] = b_msg[tid];
    for(int l=tid;l<384;l+=256) s_wc[l] = w_coor[l];
    for(int l=tid;l<600;l+=256) s_A2[l] = A2[l];
    if(tid<100) s_a1[tid] = a1v[tid];
    if(tid<8)   s_a2[tid] = (tid<6) ? a2v[tid] : 0.f;
    if(tid==0)  s_dyt[0] = dalpha[0];
    if(tid<6){ s_dyt[1+tid] = dw[tid]; s_dyt[8+tid] = db[tid]; }

    int node = tid>>3, p = tid&7;                  // 32 nodes x 8 parts
    unsigned short* myh = &hist[tid*NATOMS];
    #pragma unroll
    for(int a=0;a<NATOMS;a++) myh[a] = 0;
    __syncthreads();

    // --- phase A: per-node neighbor-atom histogram from bitmask ------------
    int lrow = tile*32 + node;
    const unsigned* mrow = &mask[(size_t)(g*Nn + lrow)*64 + p*8];
    unsigned wbits[8];
    *(uint4*)&wbits[0] = *(const uint4*)&mrow[0];
    *(uint4*)&wbits[4] = *(const uint4*)&mrow[4];
    #pragma unroll
    for(int i=0;i<8;i++){
        unsigned m = wbits[i];
        int base = (p*8 + i)*32;
        while(m){
            int bpos = __ffs(m) - 1;
            m &= m - 1;
            myh[sid[base + bpos]]++;
        }
    }
    __syncthreads();

    // --- phase A2: v = embed[own] + (sum_a cnt_a * embed[a]) / max(deg,1) ---
    {
        float cnt[NATOMS]; float deg = 0.f;
        #pragma unroll
        for(int a=0;a<NATOMS;a++){
            int c = 0;
            #pragma unroll
            for(int q=0;q<8;q++) c += hist[(node*8+q)*NATOMS + a];
            cnt[a] = (float)c; deg += cnt[a];
        }
        float inv = 1.0f/fmaxf(deg, 1.0f);
        int oid = sid[lrow];
        int d0 = p*16;
        float vv[16];
        #pragma unroll
        for(int d=0;d<16;d++) vv[d] = 0.f;
        #pragma unroll
        for(int a=0;a<NATOMS;a++){
            float ca = cnt[a];
            #pragma unroll
            for(int d=0;d<16;d++) vv[d] += ca*emb[a*128 + d0 + d];
        }
        #pragma unroll
        for(int d=0;d<16;d++) v[node][d0+d] = emb[oid*128 + d0 + d] + vv[d]*inv;
    }
    __syncthreads();

    // --- phase B: hout = gelu(v @ W_msg + b_msg), 32x128x128 ---------------
    int tx = tid&15, ty = tid>>4;                  // 2 rows x (4+4) cols
    float acc[2][8] = {};
    for(int k0=0;k0<128;k0+=32){
        #pragma unroll
        for(int i=0;i<4;i++){
            int l = tid + i*256; int k = l>>5, c4 = (l&31)*4;
            *(float4*)&wt[k][c4] = *(const float4*)&W_msg[(size_t)(k0+k)*128 + c4];
        }
        __syncthreads();
        #pragma unroll
        for(int kk=0;kk<32;kk+=4){
            float a0[4], a1r[4];
            *(float4*)a0  = *(const float4*)&v[2*ty][k0+kk];
            *(float4*)a1r = *(const float4*)&v[2*ty+1][k0+kk];
            #pragma unroll
            for(int u=0;u<4;u++){
                float4 b0 = *(const float4*)&wt[kk+u][tx*4];
                float4 b1 = *(const float4*)&wt[kk+u][64+tx*4];
                acc[0][0]+=a0[u]*b0.x; acc[0][1]+=a0[u]*b0.y; acc[0][2]+=a0[u]*b0.z; acc[0][3]+=a0[u]*b0.w;
                acc[0][4]+=a0[u]*b1.x; acc[0][5]+=a0[u]*b1.y; acc[0][6]+=a0[u]*b1.z; acc[0][7]+=a0[u]*b1.w;
                acc[1][0]+=a1r[u]*b0.x; acc[1][1]+=a1r[u]*b0.y; acc[1][2]+=a1r[u]*b0.z; acc[1][3]+=a1r[u]*b0.w;
                acc[1][4]+=a1r[u]*b1.x; acc[1][5]+=a1r[u]*b1.y; acc[1][6]+=a1r[u]*b1.z; acc[1][7]+=a1r[u]*b1.w;
            }
        }
        __syncthreads();
    }
    #pragma unroll
    for(int r=0;r<2;r++){                          // overwrite v with hout
        int row = 2*ty + r;
        #pragma unroll
        for(int j=0;j<4;j++){
            v[row][tx*4+j]    = gelu_f(acc[r][j]   + s_bm[tx*4+j]);
            v[row][64+tx*4+j] = gelu_f(acc[r][4+j] + s_bm[64+tx*4+j]);
        }
    }
    __syncthreads();

    // --- phase C: outputs ---------------------------------------------------
    // z (coalesced float4)
    #pragma unroll
    for(int i=0;i<4;i++){
        int l = tid + i*256; int row = l>>5; int c4 = (l&31)*4;
        *(float4*)&out_z[(size_t)(gn0+row)*128 + c4] = *(const float4*)&v[row][c4];
    }
    // coors_out = coords + tanh(hout @ w_coor)
    if(tid<32){
        float d0=0.f, d1=0.f, d2=0.f;
        #pragma unroll 4
        for(int k=0;k<128;k++){
            float h = v[tid][k];
            d0 += h*s_wc[k*3+0]; d1 += h*s_wc[k*3+1]; d2 += h*s_wc[k*3+2];
        }
        size_t o = (size_t)(gn0+tid)*3;
        out_co[o+0] = coords[o+0] + tanhf(d0);
        out_co[o+1] = coords[o+1] + tanhf(d1);
        out_co[o+2] = coords[o+2] + tanhf(d2);
    }
    // t1 = gelu(hout @ A1 + a1)  (arena reused for A1 k-tiles)
    float t1acc[25] = {};
    for(int k0=0;k0<128;k0+=32){
        __syncthreads();
        for(int l=tid;l<3200;l+=256) a1t[l] = A1[(size_t)k0*100 + l];
        __syncthreads();
        if(tid<128){
            int n = tid>>2, q = tid&3;             // 32 nodes x 4 x 25 dims
            #pragma unroll 4
            for(int k=0;k<32;k++){
                float h = v[n][k0+k];
                #pragma unroll
                for(int i=0;i<25;i++) t1acc[i] += h*a1t[k*100 + q*25 + i];
            }
        }
    }
    float* t1s = (float*)wt;                       // reuse W_msg tile buffer
    __syncthreads();
    if(tid<128){
        int n = tid>>2, q = tid&3;
        #pragma unroll
        for(int i=0;i<25;i++) t1s[n*100 + q*25 + i] = gelu_f(t1acc[i] + s_a1[q*25+i]);
    }
    __syncthreads();
    // t2 = gelu(t1@A2+a2); dyt; angles = tanh(...)
    if(tid<32){
        size_t o = (size_t)(gn0+tid)*6;
        #pragma unroll
        for(int j=0;j<6;j++){
            float s = s_a2[j];
            for(int k=0;k<100;k++) s += t1s[tid*100+k]*s_A2[k*6+j];
            float t2 = gelu_f(s);
            float u = tanhf(s_dyt[0]*t2)*s_dyt[1+j] + s_dyt[8+j];
            out_ang[o+j] = tanhf(u);
        }
    }
}

// ---------------------------------------------------------------------------
extern "C" void kernel_launch(void* const* d_in, const int* in_sizes, int n_in,
                              void* d_out, int out_size, void* d_ws, size_t ws_size,
                              hipStream_t stream) {
    const float* x      = (const float*)d_in[0];
    const float* coords = (const float*)d_in[1];
    const int*   ei     = (const int*)d_in[2];
    // d_in[3] = batch (implied by layout; unused)
    const float* gamma  = (const float*)d_in[4];
    const float* beta   = (const float*)d_in[5];
    const float* W1     = (const float*)d_in[6];
    const float* b1     = (const float*)d_in[7];
    const float* W2     = (const float*)d_in[8];
    const float* b2     = (const float*)d_in[9];
    const float* W3     = (const float*)d_in[10];
    const float* b3     = (const float*)d_in[11];
    const float* embed  = (const float*)d_in[12];
    const float* W_msg  = (const float*)d_in[13];
    const float* b_msg  = (const float*)d_in[14];
    const float* w_coor = (const float*)d_in[15];
    const float* A1     = (const float*)d_in[16];
    const float* a1v    = (const float*)d_in[17];
    const float* A2     = (const float*)d_in[18];
    const float* a2v    = (const float*)d_in[19];
    const float* dalpha = (const float*)d_in[20];
    const float* dw     = (const float*)d_in[21];
    const float* db     = (const float*)d_in[22];

    // workspace layout: [ids 128KB][stats 2KB] ... @1MB: h1 (33.5MB) -> mask (8MB)
    // (mask reuses h1's region AFTER gemm23 consumed h1; total ws use ~34.6MB)
    char* ws = (char*)d_ws;
    int*      ids   = (int*)ws;
    float*    stats = (float*)(ws + 131072);
    char*     big   = ws + (1<<20);
    float*    h1    = (float*)big;
    unsigned* mask  = (unsigned*)big;

    float* out_ang = (float*)d_out;
    float* out_z   = out_ang + (size_t)NT*OUTC;
    float* out_co  = out_z   + (size_t)NT*DIMd;

    hipMemsetAsync(stats, 0, 2*INC*sizeof(float), stream);
    bn_stats_k<<<256, 256, 0, stream>>>(x, stats);
    gemm1_k<<<2048, 256, 0, stream>>>(x, stats, gamma, beta, W1, b1, h1);
    gemm23_k<<<512, 256, 0, stream>>>(h1, W2, b2, W3, b3, ids);
    // h1 consumed; reuse region as adjacency bitmask
    hipMemsetAsync(mask, 0, (size_t)NT*64*sizeof(unsigned), stream);
    build_adj_k<<<Ee/256, 256, 0, stream>>>(ei, mask);
    msg_out_k<<<Bg*64, 256, 0, stream>>>(ids, mask, embed, W_msg, b_msg, w_coor,
        A1, a1v, A2, a2v, dalpha, dw, db, coords, out_ang, out_z, out_co);
}

// Round 2
// 428.839 us; speedup vs baseline: 1.1022x; 1.1022x over previous
//
#include <hip/hip_runtime.h>
#include <hip/hip_bf16.h>
#include <math.h>

// Problem constants (match reference)
#define Bg 16
#define Nn 2048
#define Ee (1<<20)
#define NT (Bg*Nn)
#define INC 256
#define DIMd 128
#define OUTC 6
#define ENCH 100
#define NATOMS 20

__device__ __forceinline__ float gelu_f(float x){
    return 0.5f*x*(1.0f+erff(x*0.70710678118654752440f));
}
__device__ __forceinline__ unsigned short f2b(float f){
    __hip_bfloat16 h = __float2bfloat16(f);
    return *(unsigned short*)&h;
}
__device__ __forceinline__ float b2f(unsigned short u){
    unsigned v = ((unsigned)u)<<16;
    return __uint_as_float(v);
}

// ---------------- Kernel 1: BatchNorm statistics (sum, sumsq per channel) ----
__global__ __launch_bounds__(256) void bn_stats_k(const float* __restrict__ x,
                                                  float* __restrict__ stats){
    int c = threadIdx.x;                 // channel
    int r0 = blockIdx.x * 128;           // 256 blocks x 128 rows = 32768
    const float* p = x + (size_t)r0*INC + c;
    float s = 0.f, s2 = 0.f;
    #pragma unroll 8
    for(int r=0;r<128;r++){ float v = p[(size_t)r*INC]; s += v; s2 += v*v; }
    atomicAdd(&stats[c], s);
    atomicAdd(&stats[INC+c], s2);
}

// ---------------- Kernel 2a: h1 = gelu(BN(x) @ W1 + b1)  [32768,256]x[256,256]
__global__ __launch_bounds__(256) void gemm1_k(const float* __restrict__ x,
        const float* __restrict__ stats, const float* __restrict__ gamma,
        const float* __restrict__ beta, const float* __restrict__ W1,
        const float* __restrict__ b1, float* __restrict__ h1){
    __shared__ float sc[INC], sh[INC];
    __shared__ float sA[64][36];   // pad 36: 16B-aligned rows, <=2-way banks
    __shared__ float sB[32][64];
    int tid = threadIdx.x;
    {   // per-channel scale/shift from global sums (cheap, redundant per block)
        float mu  = stats[tid]*(1.0f/NT);
        float var = stats[INC+tid]*(1.0f/NT) - mu*mu;
        float s = gamma[tid]/sqrtf(var + 1e-5f);
        sc[tid] = s; sh[tid] = beta[tid] - mu*s;
    }
    __syncthreads();
    int mb = blockIdx.x>>2, nb = blockIdx.x&3;     // 512 x 4 blocks
    int row0 = mb*64, n0 = nb*64;
    int tx = tid&15, ty = tid>>4;                  // 16x16 threads, 4x4 microtile
    float acc[4][4] = {};
    for(int k0=0;k0<INC;k0+=32){
        #pragma unroll
        for(int i=0;i<2;i++){                      // A tile 64x32, BN applied
            int l = tid + i*256;
            int r = l>>3, kq = (l&7)*4;
            float4 vx = *(const float4*)&x[(size_t)(row0+r)*INC + k0+kq];
            int k = k0+kq;
            sA[r][kq+0]=vx.x*sc[k+0]+sh[k+0];
            sA[r][kq+1]=vx.y*sc[k+1]+sh[k+1];
            sA[r][kq+2]=vx.z*sc[k+2]+sh[k+2];
            sA[r][kq+3]=vx.w*sc[k+3]+sh[k+3];
        }
        #pragma unroll
        for(int i=0;i<2;i++){                      // B tile 32x64
            int l = tid + i*256;
            int k = l>>4, c4 = (l&15)*4;
            *(float4*)&sB[k][c4] = *(const float4*)&W1[(size_t)(k0+k)*INC + n0 + c4];
        }
        __syncthreads();
        #pragma unroll
        for(int kk=0;kk<32;kk+=4){
            float ar[4][4];
            #pragma unroll
            for(int r=0;r<4;r++) *(float4*)&ar[r][0] = *(const float4*)&sA[ty*4+r][kk];
            #pragma unroll
            for(int u=0;u<4;u++){
                float4 b = *(const float4*)&sB[kk+u][tx*4];
                #pragma unroll
                for(int r=0;r<4;r++){
                    float a = ar[r][u];
                    acc[r][0]+=a*b.x; acc[r][1]+=a*b.y;
                    acc[r][2]+=a*b.z; acc[r][3]+=a*b.w;
                }
            }
        }
        __syncthreads();
    }
    float4 bv = *(const float4*)&b1[n0+tx*4];
    #pragma unroll
    for(int r=0;r<4;r++){
        float4 o;
        o.x = gelu_f(acc[r][0]+bv.x);
        o.y = gelu_f(acc[r][1]+bv.y);
        o.z = gelu_f(acc[r][2]+bv.z);
        o.w = gelu_f(acc[r][3]+bv.w);
        *(float4*)&h1[(size_t)(row0+ty*4+r)*INC + n0+tx*4] = o;
    }
}

// ------- Kernel 2b: h2 = gelu(h1@W2+b2); logits = h2@W3+b3; ids = argmax ----
__global__ __launch_bounds__(256) void gemm23_k(const float* __restrict__ h1,
     const float* __restrict__ W2, const float* __restrict__ b2,
     const float* __restrict__ W3, const float* __restrict__ b3,
     int* __restrict__ ids){
    __shared__ float sA[64][36];
    __shared__ float sB[32][128];   // W2 k-tile; reused for W3 [128][20]
    __shared__ float h2s[64][132];
    __shared__ float lgs[64][20];
    int tid = threadIdx.x;
    int row0 = blockIdx.x*64;       // 512 blocks
    int tx = tid&15, ty = tid>>4;   // 4 rows x 8 cols (split 4+4) per thread
    float acc[4][8] = {};
    for(int k0=0;k0<256;k0+=32){
        #pragma unroll
        for(int i=0;i<2;i++){
            int l = tid + i*256; int r = l>>3, kq = (l&7)*4;
            *(float4*)&sA[r][kq] = *(const float4*)&h1[(size_t)(row0+r)*256 + k0+kq];
        }
        #pragma unroll
        for(int i=0;i<4;i++){
            int l = tid + i*256; int k = l>>5, c4 = (l&31)*4;
            *(float4*)&sB[k][c4] = *(const float4*)&W2[(size_t)(k0+k)*128 + c4];
        }
        __syncthreads();
        #pragma unroll
        for(int kk=0;kk<32;kk+=4){
            float ar[4][4];
            #pragma unroll
            for(int r=0;r<4;r++) *(float4*)&ar[r][0] = *(const float4*)&sA[ty*4+r][kk];
            #pragma unroll
            for(int u=0;u<4;u++){
                float4 b0 = *(const float4*)&sB[kk+u][tx*4];
                float4 bq = *(const float4*)&sB[kk+u][64+tx*4];
                #pragma unroll
                for(int r=0;r<4;r++){
                    float a = ar[r][u];
                    acc[r][0]+=a*b0.x; acc[r][1]+=a*b0.y; acc[r][2]+=a*b0.z; acc[r][3]+=a*b0.w;
                    acc[r][4]+=a*bq.x; acc[r][5]+=a*bq.y; acc[r][6]+=a*bq.z; acc[r][7]+=a*bq.w;
                }
            }
        }
        __syncthreads();
    }
    float4 c0 = *(const float4*)&b2[tx*4];
    float4 c1 = *(const float4*)&b2[64+tx*4];
    #pragma unroll
    for(int r=0;r<4;r++){
        int row = ty*4+r;
        h2s[row][tx*4+0]    = gelu_f(acc[r][0]+c0.x);
        h2s[row][tx*4+1]    = gelu_f(acc[r][1]+c0.y);
        h2s[row][tx*4+2]    = gelu_f(acc[r][2]+c0.z);
        h2s[row][tx*4+3]    = gelu_f(acc[r][3]+c0.w);
        h2s[row][64+tx*4+0] = gelu_f(acc[r][4]+c1.x);
        h2s[row][64+tx*4+1] = gelu_f(acc[r][5]+c1.y);
        h2s[row][64+tx*4+2] = gelu_f(acc[r][6]+c1.z);
        h2s[row][64+tx*4+3] = gelu_f(acc[r][7]+c1.w);
    }
    float* w3s = (float*)sB;                       // reuse (W2 tile done)
    for(int l=tid;l<128*20;l+=256) w3s[l] = W3[l];
    __syncthreads();
    int n = tid>>2, q = tid&3;                     // 64 nodes x 4 col-groups
    float lg[5] = {};
    #pragma unroll 4
    for(int k=0;k<128;k++){
        float h = h2s[n][k];
        #pragma unroll
        for(int a=0;a<5;a++) lg[a] += h*w3s[k*20 + q*5 + a];
    }
    #pragma unroll
    for(int a=0;a<5;a++) lgs[n][q*5+a] = lg[a] + b3[q*5+a];
    __syncthreads();
    if(tid<64){                                    // numpy argmax: first max wins
        float best = lgs[tid][0]; int bi = 0;
        #pragma unroll
        for(int a=1;a<20;a++){ float v2 = lgs[tid][a]; if(v2>best){best=v2;bi=a;} }
        ids[row0+tid] = bi;
    }
}

// ---------------- Kernel 3: edge list -> dedup adjacency bitmask -------------
__global__ __launch_bounds__(256) void build_adj_k(const int* __restrict__ ei,
                                                   unsigned* __restrict__ mask){
    int e = blockIdx.x*256 + threadIdx.x;          // 4096 blocks, e < 2^20
    int s = ei[e], d = ei[Ee+e];
    if((s>>11) == (d>>11)){                        // intra-graph only (N=2048)
        int ld = d & (Nn-1);
        atomicOr(&mask[(size_t)s*64 + (ld>>5)], 1u<<(ld&31));
    }
}

// -------- Kernel 4: aggregation (bit-slice histogram) + message GEMM + heads -
// 64 nodes/block, 512 blocks. All phases use >=192 of 256 threads; no LDS RMW.
__global__ __launch_bounds__(256,4) void msg_out_k(
    const int* __restrict__ ids, const unsigned* __restrict__ mask,
    const float* __restrict__ embed, const float* __restrict__ W_msg,
    const float* __restrict__ b_msg, const float* __restrict__ w_coor,
    const float* __restrict__ A1, const float* __restrict__ a1v,
    const float* __restrict__ A2, const float* __restrict__ a2v,
    const float* __restrict__ dalpha, const float* __restrict__ dw,
    const float* __restrict__ db, const float* __restrict__ coords,
    float* __restrict__ out_ang, float* __restrict__ out_z,
    float* __restrict__ out_co)
{
    // v (and later hout) as bf16: 64 x 136 u16 (pad keeps rows 8B-aligned and
    // row-stride 68 dwords == 4 mod 32 -> distinct banks for 4-row reads)
    __shared__ unsigned short v_bf[64][136];                 // 17408 B
    // arena phase 1: ind[20][64] u32 (5120) | sid[2048] u8 | emb[20][128] f32
    // arena phase 2: wt = W_msg k-tile [32][128] f32 (16384)
    // arena phase 3: a1t = A1 k-tile [32][104] f32 (13312) -> t1s [64][104] bf16
    __shared__ __align__(16) unsigned char arena[17408];
    __shared__ float s_bm[128];
    __shared__ float s_wc[384];
    __shared__ float s_A2[624];    // [104][6], rows 100..103 zero
    __shared__ float s_a1[104];    // zero-padded
    __shared__ float s_dyt[16];
    __shared__ float s_a2[8];

    unsigned*       ind = (unsigned*)arena;
    unsigned char*  sid = arena + 5120;
    float*          emb = (float*)(arena + 7168);
    float*          wt  = (float*)arena;
    float*          a1t = (float*)arena;
    unsigned short* t1s = (unsigned short*)arena;

    int tid = threadIdx.x;
    int g = blockIdx.x >> 5, tile = blockIdx.x & 31;
    int gn0 = g*Nn + tile*64;
    int lane = tid & 63, wid = tid >> 6;

    // --- cooperative loads --------------------------------------------------
    for(int l=tid;l<NATOMS*128;l+=256) emb[l] = embed[l];
    #pragma unroll
    for(int i=0;i<8;i++){ int j = tid + i*256; sid[j] = (unsigned char)ids[g*Nn + j]; }
    if(tid<128) s_bm[tid] = b_msg[tid];
    if(tid<104) s_a1[tid] = (tid<100) ? a1v[tid] : 0.f;
    for(int l=tid;l<384;l+=256) s_wc[l] = w_coor[l];
    for(int l=tid;l<624;l+=256) s_A2[l] = (l<600) ? A2[l] : 0.f;
    if(tid==0)  s_dyt[0] = dalpha[0];
    if(tid<6){ s_dyt[1+tid] = dw[tid]; s_dyt[8+tid] = db[tid]; }
    if(tid<8)  s_a2[tid] = (tid<6) ? a2v[tid] : 0.f;

    int node = tid>>2, p = tid&3;                  // 64 nodes x 4 lanes
    // start adjacency-row loads early (global, independent of LDS)
    const unsigned* mrow = &mask[((size_t)(g*Nn + tile*64 + node))*64 + p*16];
    uint4 m0 = *(const uint4*)&mrow[0];
    uint4 m1 = *(const uint4*)&mrow[4];
    uint4 m2 = *(const uint4*)&mrow[8];
    uint4 m3 = *(const uint4*)&mrow[12];
    __syncthreads();

    // --- per-atom indicator bitmasks via ballot (no atomics, no divergence) --
    for(int wp=wid; wp<32; wp+=4){
        int a = sid[wp*64 + lane];
        #pragma unroll
        for(int atom=0; atom<NATOMS; atom++){
            unsigned long long bm = __ballot(a==atom);
            if(lane<2) ind[atom*64 + wp*2 + lane] = (unsigned)(bm >> (32*lane));
        }
    }
    __syncthreads();

    // --- per-node neighbor-atom counts: popcount(mask & ind), 4-lane split ---
    unsigned mw[16];
    *(uint4*)&mw[0]=m0; *(uint4*)&mw[4]=m1; *(uint4*)&mw[8]=m2; *(uint4*)&mw[12]=m3;
    int degi = 0;
    #pragma unroll
    for(int w=0;w<16;w++) degi += __popc(mw[w]);
    float cnt[NATOMS];
    #pragma unroll
    for(int a=0;a<NATOMS;a++){
        int c = 0;
        const unsigned* ia = &ind[a*64 + p*16];
        #pragma unroll
        for(int w=0;w<16;w++) c += __popc(mw[w] & ia[w]);
        cnt[a] = (float)c;
    }
    #pragma unroll
    for(int a=0;a<NATOMS;a++){
        cnt[a] += __shfl_xor(cnt[a],1,64);
        cnt[a] += __shfl_xor(cnt[a],2,64);
    }
    float deg = (float)degi;
    deg += __shfl_xor(deg,1,64);
    deg += __shfl_xor(deg,2,64);

    // --- v = emb[own] + (sum_a cnt_a emb_a)/max(deg,1); lane owns 32 dims ----
    {
        float inv = 1.0f / fmaxf(deg, 1.0f);
        int oid = sid[tile*64 + node];
        int d0 = p*32;
        float vv[32];
        #pragma unroll
        for(int d=0;d<32;d++) vv[d]=0.f;
        #pragma unroll
        for(int a=0;a<NATOMS;a++){
            float ca = cnt[a];
            const float* ea = &emb[a*128 + d0];
            #pragma unroll
            for(int d=0;d<32;d+=4){
                float4 e = *(const float4*)&ea[d];
                vv[d]+=ca*e.x; vv[d+1]+=ca*e.y; vv[d+2]+=ca*e.z; vv[d+3]+=ca*e.w;
            }
        }
        const float* eo = &emb[oid*128 + d0];
        unsigned short* dst = &v_bf[node][d0];
        #pragma unroll
        for(int d=0;d<32;d+=4){
            float4 e = *(const float4*)&eo[d];
            ushort4 o;
            o.x = f2b(e.x + vv[d]*inv);
            o.y = f2b(e.y + vv[d+1]*inv);
            o.z = f2b(e.z + vv[d+2]*inv);
            o.w = f2b(e.w + vv[d+3]*inv);
            *(ushort4*)&dst[d] = o;
        }
    }

    // --- hout GEMM: 64x128x128, 4x8 microtile, W_msg tiled 32 rows ----------
    int tx = tid&15, ty = tid>>4;
    float acc[4][8] = {};
    for(int k0=0;k0<128;k0+=32){
        __syncthreads();                            // prior tile / arena free
        for(int l=tid;l<1024;l+=256)
            ((float4*)wt)[l] = ((const float4*)(W_msg + (size_t)k0*128))[l];
        __syncthreads();
        #pragma unroll
        for(int kk=0;kk<32;kk+=4){
            float af[4][4];
            #pragma unroll
            for(int r=0;r<4;r++){
                ushort4 av = *(const ushort4*)&v_bf[ty*4+r][k0+kk];
                af[r][0]=b2f(av.x); af[r][1]=b2f(av.y); af[r][2]=b2f(av.z); af[r][3]=b2f(av.w);
            }
            #pragma unroll
            for(int u=0;u<4;u++){
                float4 b0 = *(const float4*)&wt[(kk+u)*128 + tx*4];
                float4 b1 = *(const float4*)&wt[(kk+u)*128 + 64 + tx*4];
                #pragma unroll
                for(int r=0;r<4;r++){
                    float a = af[r][u];
                    acc[r][0]+=a*b0.x; acc[r][1]+=a*b0.y; acc[r][2]+=a*b0.z; acc[r][3]+=a*b0.w;
                    acc[r][4]+=a*b1.x; acc[r][5]+=a*b1.y; acc[r][6]+=a*b1.z; acc[r][7]+=a*b1.w;
                }
            }
        }
    }
    __syncthreads();                                // all v_bf reads done

    // --- epilogue: z (fp32, straight from regs) + hout -> v_bf (bf16) -------
    {
        float4 bm0 = *(const float4*)&s_bm[tx*4];
        float4 bm1 = *(const float4*)&s_bm[64+tx*4];
        #pragma unroll
        for(int r=0;r<4;r++){
            int row = ty*4+r;
            float h0=gelu_f(acc[r][0]+bm0.x), h1=gelu_f(acc[r][1]+bm0.y);
            float h2=gelu_f(acc[r][2]+bm0.z), h3=gelu_f(acc[r][3]+bm0.w);
            float h4=gelu_f(acc[r][4]+bm1.x), h5=gelu_f(acc[r][5]+bm1.y);
            float h6=gelu_f(acc[r][6]+bm1.z), h7=gelu_f(acc[r][7]+bm1.w);
            *(float4*)&out_z[(size_t)(gn0+row)*128 + tx*4]    = make_float4(h0,h1,h2,h3);
            *(float4*)&out_z[(size_t)(gn0+row)*128 + 64+tx*4] = make_float4(h4,h5,h6,h7);
            ushort4 q0; q0.x=f2b(h0); q0.y=f2b(h1); q0.z=f2b(h2); q0.w=f2b(h3);
            ushort4 q1; q1.x=f2b(h4); q1.y=f2b(h5); q1.z=f2b(h6); q1.w=f2b(h7);
            *(ushort4*)&v_bf[row][tx*4]    = q0;
            *(ushort4*)&v_bf[row][64+tx*4] = q1;
        }
    }
    __syncthreads();

    // --- coors: 4-lane k-split dot with w_coor, shfl reduce ------------------
    {
        float d0=0.f, d1=0.f, d2=0.f;
        int kb = p*32;
        #pragma unroll
        for(int k=0;k<32;k+=4){
            ushort4 hv = *(const ushort4*)&v_bf[node][kb+k];
            float h0=b2f(hv.x),h1=b2f(hv.y),h2=b2f(hv.z),h3=b2f(hv.w);
            const float* wc = &s_wc[(kb+k)*3];
            d0 += h0*wc[0]+h1*wc[3]+h2*wc[6]+h3*wc[9];
            d1 += h0*wc[1]+h1*wc[4]+h2*wc[7]+h3*wc[10];
            d2 += h0*wc[2]+h1*wc[5]+h2*wc[8]+h3*wc[11];
        }
        d0 += __shfl_xor(d0,1,64); d0 += __shfl_xor(d0,2,64);
        d1 += __shfl_xor(d1,1,64); d1 += __shfl_xor(d1,2,64);
        d2 += __shfl_xor(d2,1,64); d2 += __shfl_xor(d2,2,64);
        if(p==0){
            size_t o = (size_t)(gn0+node)*3;
            out_co[o+0] = coords[o+0] + tanhf(d0);
            out_co[o+1] = coords[o+1] + tanhf(d1);
            out_co[o+2] = coords[o+2] + tanhf(d2);
        }
    }

    // --- t1 = gelu(hout @ A1 + a1): 64x104(pad)x128 tiled GEMM --------------
    float t1a[4][8] = {};
    bool has2 = (tx < 10);                          // cols 64+tx*4 < 104
    for(int k0=0;k0<128;k0+=32){
        __syncthreads();
        for(int l=tid;l<832;l+=256){                // 32 rows x 26 float4 (pad 0)
            int k = l/26, c = l - k*26;
            float4 val = make_float4(0.f,0.f,0.f,0.f);
            if(c<25) val = *(const float4*)&A1[(size_t)(k0+k)*100 + c*4];
            ((float4*)&a1t[k*104])[c] = val;
        }
        __syncthreads();
        #pragma unroll
        for(int kk=0;kk<32;kk+=4){
            float af[4][4];
            #pragma unroll
            for(int r=0;r<4;r++){
                ushort4 av = *(const ushort4*)&v_bf[ty*4+r][k0+kk];
                af[r][0]=b2f(av.x); af[r][1]=b2f(av.y); af[r][2]=b2f(av.z); af[r][3]=b2f(av.w);
            }
            #pragma unroll
            for(int u=0;u<4;u++){
                float4 b0 = *(const float4*)&a1t[(kk+u)*104 + tx*4];
                // tx>=10 reads past row end (stays in arena; results discarded)
                float4 b1 = *(const float4*)&a1t[(kk+u)*104 + 64 + tx*4];
                #pragma unroll
                for(int r=0;r<4;r++){
                    float a = af[r][u];
                    t1a[r][0]+=a*b0.x; t1a[r][1]+=a*b0.y; t1a[r][2]+=a*b0.z; t1a[r][3]+=a*b0.w;
                    t1a[r][4]+=a*b1.x; t1a[r][5]+=a*b1.y; t1a[r][6]+=a*b1.z; t1a[r][7]+=a*b1.w;
                }
            }
        }
    }
    __syncthreads();                                // a1t reads done
    {
        float4 a10 = *(const float4*)&s_a1[tx*4];
        #pragma unroll
        for(int r=0;r<4;r++){
            int row = ty*4+r;
            ushort4 q0;
            q0.x = f2b(gelu_f(t1a[r][0]+a10.x));
            q0.y = f2b(gelu_f(t1a[r][1]+a10.y));
            q0.z = f2b(gelu_f(t1a[r][2]+a10.z));
            q0.w = f2b(gelu_f(t1a[r][3]+a10.w));
            *(ushort4*)&t1s[row*104 + tx*4] = q0;
            if(has2){
                float4 a11 = *(const float4*)&s_a1[64+tx*4];
                ushort4 q1;
                q1.x = f2b(gelu_f(t1a[r][4]+a11.x));
                q1.y = f2b(gelu_f(t1a[r][5]+a11.y));
                q1.z = f2b(gelu_f(t1a[r][6]+a11.z));
                q1.w = f2b(gelu_f(t1a[r][7]+a11.w));
                *(ushort4*)&t1s[row*104 + 64 + tx*4] = q1;
            }
        }
    }
    __syncthreads();

    // --- t2 = gelu(t1@A2+a2); DyT; angles = tanh(...); 4-lane k-split --------
    {
        int g0 = (p<2) ? p*7 : 14+(p-2)*6;          // float4-groups of k
        int gcount = (p<2) ? 7 : 6;
        float s[6] = {0.f,0.f,0.f,0.f,0.f,0.f};
        for(int gg=0; gg<gcount; gg++){
            int kb = (g0+gg)*4;
            ushort4 tv = *(const ushort4*)&t1s[node*104 + kb];
            float u0=b2f(tv.x), u1=b2f(tv.y), u2=b2f(tv.z), u3=b2f(tv.w);
            #pragma unroll
            for(int j=0;j<6;j++)
                s[j] += u0*s_A2[kb*6+j] + u1*s_A2[(kb+1)*6+j]
                      + u2*s_A2[(kb+2)*6+j] + u3*s_A2[(kb+3)*6+j];
        }
        #pragma unroll
        for(int j=0;j<6;j++){ s[j]+=__shfl_xor(s[j],1,64); s[j]+=__shfl_xor(s[j],2,64); }
        if(p<2){
            size_t o = (size_t)(gn0+node)*6 + p*3;
            #pragma unroll
            for(int jj=0;jj<3;jj++){
                int j = p*3+jj;
                float t2v = gelu_f(s[j] + s_a2[j]);
                float uu = tanhf(s_dyt[0]*t2v)*s_dyt[1+j] + s_dyt[8+j];
                out_ang[o+jj] = tanhf(uu);
            }
        }
    }
}

// ---------------------------------------------------------------------------
extern "C" void kernel_launch(void* const* d_in, const int* in_sizes, int n_in,
                              void* d_out, int out_size, void* d_ws, size_t ws_size,
                              hipStream_t stream) {
    const float* x      = (const float*)d_in[0];
    const float* coords = (const float*)d_in[1];
    const int*   ei     = (const int*)d_in[2];
    const float* gamma  = (const float*)d_in[4];
    const float* beta   = (const float*)d_in[5];
    const float* W1     = (const float*)d_in[6];
    const float* b1     = (const float*)d_in[7];
    const float* W2     = (const float*)d_in[8];
    const float* b2     = (const float*)d_in[9];
    const float* W3     = (const float*)d_in[10];
    const float* b3     = (const float*)d_in[11];
    const float* embed  = (const float*)d_in[12];
    const float* W_msg  = (const float*)d_in[13];
    const float* b_msg  = (const float*)d_in[14];
    const float* w_coor = (const float*)d_in[15];
    const float* A1     = (const float*)d_in[16];
    const float* a1v    = (const float*)d_in[17];
    const float* A2     = (const float*)d_in[18];
    const float* a2v    = (const float*)d_in[19];
    const float* dalpha = (const float*)d_in[20];
    const float* dw     = (const float*)d_in[21];
    const float* db     = (const float*)d_in[22];

    // ws: [ids 128KB][stats 2KB] ... @1MB: h1 (33.5MB) -> mask (8MB, reused)
    char* ws = (char*)d_ws;
    int*      ids   = (int*)ws;
    float*    stats = (float*)(ws + 131072);
    char*     big   = ws + (1<<20);
    float*    h1    = (float*)big;
    unsigned* mask  = (unsigned*)big;

    float* out_ang = (float*)d_out;
    float* out_z   = out_ang + (size_t)NT*OUTC;
    float* out_co  = out_z   + (size_t)NT*DIMd;

    hipMemsetAsync(stats, 0, 2*INC*sizeof(float), stream);
    bn_stats_k<<<256, 256, 0, stream>>>(x, stats);
    gemm1_k<<<2048, 256, 0, stream>>>(x, stats, gamma, beta, W1, b1, h1);
    gemm23_k<<<512, 256, 0, stream>>>(h1, W2, b2, W3, b3, ids);
    // h1 consumed; reuse region as adjacency bitmask
    hipMemsetAsync(mask, 0, (size_t)NT*64*sizeof(unsigned), stream);
    build_adj_k<<<Ee/256, 256, 0, stream>>>(ei, mask);
    msg_out_k<<<Bg*32, 256, 0, stream>>>(ids, mask, embed, W_msg, b_msg, w_coor,
        A1, a1v, A2, a2v, dalpha, dw, db, coords, out_ang, out_z, out_co);
}

// Round 3
// 271.904 us; speedup vs baseline: 1.7384x; 1.5772x over previous
//
#include <hip/hip_runtime.h>
#include <hip/hip_bf16.h>
#include <math.h>

// Problem constants (match reference)
#define Bg 16
#define Nn 2048
#define Ee (1<<20)
#define NT (Bg*Nn)
#define INC 256
#define DIMd 128
#define OUTC 6
#define ENCH 100
#define NATOMS 20

typedef __attribute__((ext_vector_type(8))) short bf16x8;
typedef __attribute__((ext_vector_type(4))) float f32x4;

__device__ __forceinline__ float gelu_f(float x){
    return 0.5f*x*(1.0f+erff(x*0.70710678118654752440f));
}
__device__ __forceinline__ unsigned short f2b(float f){
    __hip_bfloat16 h = __float2bfloat16(f);
    return *(unsigned short*)&h;
}
__device__ __forceinline__ float b2f(unsigned short u){
    unsigned v = ((unsigned)u)<<16;
    return __uint_as_float(v);
}
// split fp32 into bf16 hi + bf16 lo (v ~= hi + lo, dropped residual ~2^-18 rel)
__device__ __forceinline__ void splitf(float v, unsigned short& hi, unsigned short& lo){
    unsigned short h = f2b(v);
    hi = h; lo = f2b(v - b2f(h));
}

// ---------------- Kernel: BatchNorm statistics ------------------------------
__global__ __launch_bounds__(256) void bn_stats_k(const float* __restrict__ x,
                                                  float* __restrict__ stats){
    int c = threadIdx.x;
    int r0 = blockIdx.x * 128;
    const float* p = x + (size_t)r0*INC + c;
    float s = 0.f, s2 = 0.f;
    #pragma unroll 8
    for(int r=0;r<128;r++){ float v = p[(size_t)r*INC]; s += v; s2 += v*v; }
    atomicAdd(&stats[c], s);
    atomicAdd(&stats[INC+c], s2);
}

// ---------------- Kernel: edge list -> dedup adjacency bitmask --------------
__global__ __launch_bounds__(256) void build_adj_k(const int* __restrict__ ei,
                                                   unsigned* __restrict__ mask){
    int e = blockIdx.x*256 + threadIdx.x;
    int s = ei[e], d = ei[Ee+e];
    if((s>>11) == (d>>11)){
        int ld = d & (Nn-1);
        atomicOr(&mask[(size_t)s*64 + (ld>>5)], 1u<<(ld&31));
    }
}

// ---------------- Kernel: transpose+split weights to [n][k] bf16 hi/lo ------
__global__ __launch_bounds__(256) void prep_w_k(const float* __restrict__ W1,
    const float* __restrict__ W2, const float* __restrict__ Wm,
    const float* __restrict__ A1, short* __restrict__ w1th, short* __restrict__ w1tl,
    short* __restrict__ w2th, short* __restrict__ w2tl,
    short* __restrict__ wmth, short* __restrict__ wmtl,
    short* __restrict__ a1th, short* __restrict__ a1tl)
{
    int gid = blockIdx.x*256 + threadIdx.x;       // 64 blocks -> 16384 threads
    unsigned short hi, lo;
    for(int l=gid;l<65536;l+=16384){ int n=l>>8,k=l&255;
        splitf(W1[(size_t)k*256+n],hi,lo); w1th[l]=(short)hi; w1tl[l]=(short)lo; }
    for(int l=gid;l<32768;l+=16384){ int n=l>>8,k=l&255;
        splitf(W2[(size_t)k*128+n],hi,lo); w2th[l]=(short)hi; w2tl[l]=(short)lo; }
    for(int l=gid;l<16384;l+=16384){ int n=l>>7,k=l&127;
        splitf(Wm[(size_t)k*128+n],hi,lo); wmth[l]=(short)hi; wmtl[l]=(short)lo; }
    for(int l=gid;l<16384;l+=16384){ int n=l>>7,k=l&127;
        float v=(n<ENCH)? A1[(size_t)k*ENCH+n] : 0.f;
        splitf(v,hi,lo); a1th[l]=(short)hi; a1tl[l]=(short)lo; }
}

// ---------------- Kernel: h1 = gelu(BN(x)@W1+b1) via 3-term split MFMA ------
// grid 1024: mb=bx>>1 (64 rows), nb=bx&1 (128 cols). 4 waves, wave=32m x 64n.
__global__ __launch_bounds__(256) void gemm1_mfma(const float* __restrict__ x,
    const float* __restrict__ stats, const float* __restrict__ gamma,
    const float* __restrict__ beta, const short* __restrict__ w1th,
    const short* __restrict__ w1tl, const float* __restrict__ b1,
    float* __restrict__ h1)
{
    __shared__ float sc[256], sh[256];
    __shared__ short sAh[64*40], sAl[64*40];     // pad 40: 16B-aligned frag reads
    __shared__ short sBh[128*40], sBl[128*40];
    int tid = threadIdx.x;
    {
        float mu  = stats[tid]*(1.0f/NT);
        float var = stats[256+tid]*(1.0f/NT) - mu*mu;
        float s = gamma[tid]/sqrtf(var + 1e-5f);
        sc[tid] = s; sh[tid] = beta[tid] - mu*s;
    }
    int mb = blockIdx.x>>1, nb = blockIdx.x&1;
    int row0 = mb*64, n0 = nb*128;
    int lane = tid&63, w = tid>>6;
    int ln = lane&15, quad = lane>>4;
    int m0w = (w&1)*32, n0w = (w>>1)*64;
    f32x4 acc[2][4];
    #pragma unroll
    for(int i=0;i<2;i++)
        #pragma unroll
        for(int j=0;j<4;j++) acc[i][j] = (f32x4){0.f,0.f,0.f,0.f};
    __syncthreads();
    for(int k0=0;k0<256;k0+=32){
        #pragma unroll
        for(int i=0;i<2;i++){                       // A: BN(x) 64x32 split
            int id = tid + i*256; int r = id>>3, kq = (id&7)*4;
            float4 vx = *(const float4*)&x[(size_t)(row0+r)*256 + k0+kq];
            int k = k0+kq;
            float v0 = vx.x*sc[k]+sh[k],   v1 = vx.y*sc[k+1]+sh[k+1];
            float v2 = vx.z*sc[k+2]+sh[k+2], v3 = vx.w*sc[k+3]+sh[k+3];
            ushort4 hi, lo;
            splitf(v0,hi.x,lo.x); splitf(v1,hi.y,lo.y);
            splitf(v2,hi.z,lo.z); splitf(v3,hi.w,lo.w);
            *(ushort4*)&sAh[r*40+kq] = hi;
            *(ushort4*)&sAl[r*40+kq] = lo;
        }
        #pragma unroll
        for(int i=0;i<4;i++){                       // B: W1t hi/lo [128][32]
            int id = tid + i*256; int plane = id>>9, cid = id&511;
            int r = cid>>2, c = cid&3;
            const short* src = (plane? w1tl : w1th) + (size_t)(n0+r)*256 + k0 + c*8;
            short* dst = (plane? sBl : sBh) + r*40 + c*8;
            *(bf16x8*)dst = *(const bf16x8*)src;
        }
        __syncthreads();
        bf16x8 ah[2], al[2];
        #pragma unroll
        for(int tm=0;tm<2;tm++){
            ah[tm] = *(const bf16x8*)&sAh[(m0w+tm*16+ln)*40 + quad*8];
            al[tm] = *(const bf16x8*)&sAl[(m0w+tm*16+ln)*40 + quad*8];
        }
        #pragma unroll
        for(int tn=0;tn<4;tn++){
            bf16x8 bh = *(const bf16x8*)&sBh[(n0w+tn*16+ln)*40 + quad*8];
            bf16x8 bl = *(const bf16x8*)&sBl[(n0w+tn*16+ln)*40 + quad*8];
            #pragma unroll
            for(int tm=0;tm<2;tm++){
                acc[tm][tn] = __builtin_amdgcn_mfma_f32_16x16x32_bf16(al[tm], bh, acc[tm][tn], 0,0,0);
                acc[tm][tn] = __builtin_amdgcn_mfma_f32_16x16x32_bf16(ah[tm], bl, acc[tm][tn], 0,0,0);
                acc[tm][tn] = __builtin_amdgcn_mfma_f32_16x16x32_bf16(ah[tm], bh, acc[tm][tn], 0,0,0);
            }
        }
        __syncthreads();
    }
    #pragma unroll
    for(int tn=0;tn<4;tn++){
        int col = n0 + n0w + tn*16 + ln;
        float bias = b1[col];
        #pragma unroll
        for(int tm=0;tm<2;tm++){
            int rowb = row0 + m0w + tm*16 + quad*4;
            #pragma unroll
            for(int r=0;r<4;r++)
                h1[(size_t)(rowb+r)*256 + col] = gelu_f(acc[tm][tn][r] + bias);
        }
    }
}

// ------ Kernel: h2=gelu(h1@W2+b2) (split MFMA); logits+argmax in-block ------
// grid 512 (64 rows each), N=128. 4 waves, wave=32m x 64n.
__global__ __launch_bounds__(256) void gemm23_mfma(const float* __restrict__ h1,
    const short* __restrict__ w2th, const short* __restrict__ w2tl,
    const float* __restrict__ b2, const float* __restrict__ W3,
    const float* __restrict__ b3, int* __restrict__ ids)
{
    __shared__ short sAh[64*40], sAl[64*40];
    __shared__ short sBh[128*40], sBl[128*40];
    __shared__ float h2s[64*132];
    __shared__ float lgs[64*20];
    int tid = threadIdx.x;
    int row0 = blockIdx.x*64;
    int lane = tid&63, w = tid>>6;
    int ln = lane&15, quad = lane>>4;
    int m0w = (w&1)*32, n0w = (w>>1)*64;
    f32x4 acc[2][4];
    #pragma unroll
    for(int i=0;i<2;i++)
        #pragma unroll
        for(int j=0;j<4;j++) acc[i][j] = (f32x4){0.f,0.f,0.f,0.f};
    for(int k0=0;k0<256;k0+=32){
        #pragma unroll
        for(int i=0;i<2;i++){
            int id = tid + i*256; int r = id>>3, kq = (id&7)*4;
            float4 vx = *(const float4*)&h1[(size_t)(row0+r)*256 + k0+kq];
            ushort4 hi, lo;
            splitf(vx.x,hi.x,lo.x); splitf(vx.y,hi.y,lo.y);
            splitf(vx.z,hi.z,lo.z); splitf(vx.w,hi.w,lo.w);
            *(ushort4*)&sAh[r*40+kq] = hi;
            *(ushort4*)&sAl[r*40+kq] = lo;
        }
        #pragma unroll
        for(int i=0;i<4;i++){
            int id = tid + i*256; int plane = id>>9, cid = id&511;
            int r = cid>>2, c = cid&3;
            const short* src = (plane? w2tl : w2th) + (size_t)r*256 + k0 + c*8;
            short* dst = (plane? sBl : sBh) + r*40 + c*8;
            *(bf16x8*)dst = *(const bf16x8*)src;
        }
        __syncthreads();
        bf16x8 ah[2], al[2];
        #pragma unroll
        for(int tm=0;tm<2;tm++){
            ah[tm] = *(const bf16x8*)&sAh[(m0w+tm*16+ln)*40 + quad*8];
            al[tm] = *(const bf16x8*)&sAl[(m0w+tm*16+ln)*40 + quad*8];
        }
        #pragma unroll
        for(int tn=0;tn<4;tn++){
            bf16x8 bh = *(const bf16x8*)&sBh[(n0w+tn*16+ln)*40 + quad*8];
            bf16x8 bl = *(const bf16x8*)&sBl[(n0w+tn*16+ln)*40 + quad*8];
            #pragma unroll
            for(int tm=0;tm<2;tm++){
                acc[tm][tn] = __builtin_amdgcn_mfma_f32_16x16x32_bf16(al[tm], bh, acc[tm][tn], 0,0,0);
                acc[tm][tn] = __builtin_amdgcn_mfma_f32_16x16x32_bf16(ah[tm], bl, acc[tm][tn], 0,0,0);
                acc[tm][tn] = __builtin_amdgcn_mfma_f32_16x16x32_bf16(ah[tm], bh, acc[tm][tn], 0,0,0);
            }
        }
        __syncthreads();
    }
    #pragma unroll
    for(int tn=0;tn<4;tn++){
        int col = n0w + tn*16 + ln;
        float bias = b2[col];
        #pragma unroll
        for(int tm=0;tm<2;tm++){
            int rb = m0w + tm*16 + quad*4;
            #pragma unroll
            for(int r=0;r<4;r++)
                h2s[(rb+r)*132 + col] = gelu_f(acc[tm][tn][r] + bias);
        }
    }
    float* w3s = (float*)sBh;                       // 2560 f32 = 10240 B fits
    for(int l=tid;l<2560;l+=256) w3s[l] = W3[l];
    __syncthreads();
    int n = tid>>2, q = tid&3;
    float lg[5] = {};
    #pragma unroll 4
    for(int k=0;k<128;k++){
        float h = h2s[n*132+k];
        #pragma unroll
        for(int a=0;a<5;a++) lg[a] += h*w3s[k*20 + q*5 + a];
    }
    #pragma unroll
    for(int a=0;a<5;a++) lgs[n*20 + q*5 + a] = lg[a] + b3[q*5+a];
    __syncthreads();
    if(tid<64){                                     // numpy argmax: first max wins
        float best = lgs[tid*20]; int bi = 0;
        #pragma unroll
        for(int a=1;a<20;a++){ float v2 = lgs[tid*20+a]; if(v2>best){best=v2;bi=a;} }
        ids[row0+tid] = bi;
    }
}

// ---------------- Kernel: aggregation -> v_bf (bf16) in global --------------
// 64 nodes/block, 512 blocks; bit-slice histogram, no atomics.
__global__ __launch_bounds__(256) void agg_k(const int* __restrict__ ids,
    const unsigned* __restrict__ mask, const float* __restrict__ embed,
    unsigned short* __restrict__ vbf)
{
    __shared__ unsigned ind[NATOMS*64];
    __shared__ unsigned char sid[2048];
    __shared__ float emb[NATOMS*128];
    int tid = threadIdx.x;
    int g = blockIdx.x>>5, tile = blockIdx.x&31;
    int lane = tid&63, wid = tid>>6;
    for(int l=tid;l<NATOMS*128;l+=256) emb[l] = embed[l];
    #pragma unroll
    for(int i=0;i<8;i++){ int j = tid + i*256; sid[j] = (unsigned char)ids[g*Nn + j]; }
    int node = tid>>2, p = tid&3;
    const unsigned* mrow = &mask[((size_t)(g*Nn + tile*64 + node))*64 + p*16];
    uint4 m0 = *(const uint4*)&mrow[0];
    uint4 m1 = *(const uint4*)&mrow[4];
    uint4 m2 = *(const uint4*)&mrow[8];
    uint4 m3 = *(const uint4*)&mrow[12];
    __syncthreads();
    for(int wp=wid; wp<32; wp+=4){
        int a = sid[wp*64 + lane];
        #pragma unroll
        for(int atom=0; atom<NATOMS; atom++){
            unsigned long long bm = __ballot(a==atom);
            if(lane<2) ind[atom*64 + wp*2 + lane] = (unsigned)(bm >> (32*lane));
        }
    }
    __syncthreads();
    unsigned mw[16];
    *(uint4*)&mw[0]=m0; *(uint4*)&mw[4]=m1; *(uint4*)&mw[8]=m2; *(uint4*)&mw[12]=m3;
    int degi = 0;
    #pragma unroll
    for(int w2=0;w2<16;w2++) degi += __popc(mw[w2]);
    float cnt[NATOMS];
    #pragma unroll
    for(int a=0;a<NATOMS;a++){
        int c = 0;
        const unsigned* ia = &ind[a*64 + p*16];
        #pragma unroll
        for(int w2=0;w2<16;w2++) c += __popc(mw[w2] & ia[w2]);
        cnt[a] = (float)c;
    }
    #pragma unroll
    for(int a=0;a<NATOMS;a++){
        cnt[a] += __shfl_xor(cnt[a],1,64);
        cnt[a] += __shfl_xor(cnt[a],2,64);
    }
    float deg = (float)degi;
    deg += __shfl_xor(deg,1,64);
    deg += __shfl_xor(deg,2,64);
    {
        float inv = 1.0f / fmaxf(deg, 1.0f);
        int oid = sid[tile*64 + node];
        int d0 = p*32;
        float vv[32];
        #pragma unroll
        for(int d=0;d<32;d++) vv[d]=0.f;
        #pragma unroll
        for(int a=0;a<NATOMS;a++){
            float ca = cnt[a];
            const float* ea = &emb[a*128 + d0];
            #pragma unroll
            for(int d=0;d<32;d+=4){
                float4 e = *(const float4*)&ea[d];
                vv[d]+=ca*e.x; vv[d+1]+=ca*e.y; vv[d+2]+=ca*e.z; vv[d+3]+=ca*e.w;
            }
        }
        const float* eo = &emb[oid*128 + d0];
        unsigned short* dst = &vbf[((size_t)(g*Nn + tile*64 + node))*128 + d0];
        #pragma unroll
        for(int d=0;d<32;d+=4){
            float4 e = *(const float4*)&eo[d];
            ushort4 o;
            o.x = f2b(e.x + vv[d]*inv);
            o.y = f2b(e.y + vv[d+1]*inv);
            o.z = f2b(e.z + vv[d+2]*inv);
            o.w = f2b(e.w + vv[d+3]*inv);
            *(ushort4*)&dst[d] = o;
        }
    }
}

// ------- Kernel: hout GEMM (MFMA, 2-term W split) + z/coors/t1/t2 heads -----
// grid 512 (64 nodes each). 4 waves, wave=32m x 64n.
__global__ __launch_bounds__(256) void msg2_k(
    const unsigned short* __restrict__ vbf,
    const short* __restrict__ wmth, const short* __restrict__ wmtl,
    const float* __restrict__ b_msg, const float* __restrict__ w_coor,
    const short* __restrict__ a1th, const short* __restrict__ a1tl,
    const float* __restrict__ a1v, const float* __restrict__ A2,
    const float* __restrict__ a2v, const float* __restrict__ dalpha,
    const float* __restrict__ dw, const float* __restrict__ db,
    const float* __restrict__ coords, float* __restrict__ out_ang,
    float* __restrict__ out_z, float* __restrict__ out_co)
{
    __shared__ short sA[64*40];
    __shared__ short sBh[128*40], sBl[128*40];
    __shared__ unsigned short houts[64*136];   // hout bf16; later t1s [64][104]
    __shared__ float s_bm[128], s_wc[384], s_A2[624], s_a1[104];
    __shared__ float s_dyt[16], s_a2[8];
    int tid = threadIdx.x;
    int row0 = blockIdx.x*64;
    int lane = tid&63, w = tid>>6;
    int ln = lane&15, quad = lane>>4;
    int m0w = (w&1)*32, n0w = (w>>1)*64;

    if(tid<128) s_bm[tid] = b_msg[tid];
    if(tid<104) s_a1[tid] = (tid<ENCH) ? a1v[tid] : 0.f;
    for(int l=tid;l<384;l+=256) s_wc[l] = w_coor[l];
    for(int l=tid;l<624;l+=256) s_A2[l] = (l<600) ? A2[l] : 0.f;
    if(tid==0)  s_dyt[0] = dalpha[0];
    if(tid<6){ s_dyt[1+tid] = dw[tid]; s_dyt[8+tid] = db[tid]; }
    if(tid<8)  s_a2[tid] = (tid<6) ? a2v[tid] : 0.f;

    // ---- hout = gelu(v @ W_msg + b), 2-term W split ------------------------
    f32x4 acc[2][4];
    #pragma unroll
    for(int i=0;i<2;i++)
        #pragma unroll
        for(int j=0;j<4;j++) acc[i][j] = (f32x4){0.f,0.f,0.f,0.f};
    for(int k0=0;k0<128;k0+=32){
        {   int r = tid>>2, c = tid&3;                  // A: v tile 64x32 bf16
            *(bf16x8*)&sA[r*40+c*8] =
                *(const bf16x8*)&vbf[(size_t)(row0+r)*128 + k0 + c*8];
        }
        #pragma unroll
        for(int i=0;i<4;i++){                           // B: Wmsg_t [128][32]
            int id = tid + i*256; int plane = id>>9, cid = id&511;
            int r = cid>>2, c = cid&3;
            const short* src = (plane? wmtl : wmth) + (size_t)r*128 + k0 + c*8;
            short* dst = (plane? sBl : sBh) + r*40 + c*8;
            *(bf16x8*)dst = *(const bf16x8*)src;
        }
        __syncthreads();
        bf16x8 av[2];
        #pragma unroll
        for(int tm=0;tm<2;tm++)
            av[tm] = *(const bf16x8*)&sA[(m0w+tm*16+ln)*40 + quad*8];
        #pragma unroll
        for(int tn=0;tn<4;tn++){
            bf16x8 bh = *(const bf16x8*)&sBh[(n0w+tn*16+ln)*40 + quad*8];
            bf16x8 bl = *(const bf16x8*)&sBl[(n0w+tn*16+ln)*40 + quad*8];
            #pragma unroll
            for(int tm=0;tm<2;tm++){
                acc[tm][tn] = __builtin_amdgcn_mfma_f32_16x16x32_bf16(av[tm], bl, acc[tm][tn], 0,0,0);
                acc[tm][tn] = __builtin_amdgcn_mfma_f32_16x16x32_bf16(av[tm], bh, acc[tm][tn], 0,0,0);
            }
        }
        __syncthreads();
    }
    // epilogue: z fp32 + hout bf16 to LDS
    #pragma unroll
    for(int tn=0;tn<4;tn++){
        int col = n0w + tn*16 + ln;
        float bias = s_bm[col];
        #pragma unroll
        for(int tm=0;tm<2;tm++){
            int mb2 = m0w + tm*16 + quad*4;
            #pragma unroll
            for(int r=0;r<4;r++){
                float hv = gelu_f(acc[tm][tn][r] + bias);
                out_z[(size_t)(row0+mb2+r)*128 + col] = hv;
                houts[(mb2+r)*136 + col] = f2b(hv);
            }
        }
    }
    __syncthreads();

    // ---- coors: 4-lane k-split dot with w_coor -----------------------------
    int node = tid>>2, p = tid&3;
    {
        float d0=0.f, d1=0.f, d2=0.f;
        int kb = p*32;
        #pragma unroll
        for(int k=0;k<32;k+=4){
            ushort4 hv = *(const ushort4*)&houts[node*136 + kb + k];
            float h0=b2f(hv.x),h1=b2f(hv.y),h2=b2f(hv.z),h3=b2f(hv.w);
            const float* wc = &s_wc[(kb+k)*3];
            d0 += h0*wc[0]+h1*wc[3]+h2*wc[6]+h3*wc[9];
            d1 += h0*wc[1]+h1*wc[4]+h2*wc[7]+h3*wc[10];
            d2 += h0*wc[2]+h1*wc[5]+h2*wc[8]+h3*wc[11];
        }
        d0 += __shfl_xor(d0,1,64); d0 += __shfl_xor(d0,2,64);
        d1 += __shfl_xor(d1,1,64); d1 += __shfl_xor(d1,2,64);
        d2 += __shfl_xor(d2,1,64); d2 += __shfl_xor(d2,2,64);
        if(p==0){
            size_t o = (size_t)(row0+node)*3;
            out_co[o+0] = coords[o+0] + tanhf(d0);
            out_co[o+1] = coords[o+1] + tanhf(d1);
            out_co[o+2] = coords[o+2] + tanhf(d2);
        }
    }

    // ---- t1 = gelu(hout @ A1 + a1), 2-term split, N=128 (cols>=100 zero) ---
    f32x4 acc2[2][4];
    #pragma unroll
    for(int i=0;i<2;i++)
        #pragma unroll
        for(int j=0;j<4;j++) acc2[i][j] = (f32x4){0.f,0.f,0.f,0.f};
    for(int k0=0;k0<128;k0+=32){
        __syncthreads();                    // protect sB reuse across iters
        #pragma unroll
        for(int i=0;i<4;i++){
            int id = tid + i*256; int plane = id>>9, cid = id&511;
            int r = cid>>2, c = cid&3;
            const short* src = (plane? a1tl : a1th) + (size_t)r*128 + k0 + c*8;
            short* dst = (plane? sBl : sBh) + r*40 + c*8;
            *(bf16x8*)dst = *(const bf16x8*)src;
        }
        __syncthreads();
        bf16x8 ah[2];
        #pragma unroll
        for(int tm=0;tm<2;tm++)
            ah[tm] = *(const bf16x8*)&houts[(m0w+tm*16+ln)*136 + k0 + quad*8];
        #pragma unroll
        for(int tn=0;tn<4;tn++){
            bf16x8 bh = *(const bf16x8*)&sBh[(n0w+tn*16+ln)*40 + quad*8];
            bf16x8 bl = *(const bf16x8*)&sBl[(n0w+tn*16+ln)*40 + quad*8];
            #pragma unroll
            for(int tm=0;tm<2;tm++){
                acc2[tm][tn] = __builtin_amdgcn_mfma_f32_16x16x32_bf16(ah[tm], bl, acc2[tm][tn], 0,0,0);
                acc2[tm][tn] = __builtin_amdgcn_mfma_f32_16x16x32_bf16(ah[tm], bh, acc2[tm][tn], 0,0,0);
            }
        }
    }
    __syncthreads();                        // houts reads done -> reuse as t1s
    unsigned short* t1s = houts;            // [64][104]
    #pragma unroll
    for(int tn=0;tn<4;tn++){
        int col = n0w + tn*16 + ln;
        if(col < 104){
            float bias = s_a1[col];
            #pragma unroll
            for(int tm=0;tm<2;tm++){
                int mb2 = m0w + tm*16 + quad*4;
                #pragma unroll
                for(int r=0;r<4;r++)
                    t1s[(mb2+r)*104 + col] = f2b(gelu_f(acc2[tm][tn][r] + bias));
            }
        }
    }
    __syncthreads();

    // ---- t2 = gelu(t1@A2+a2); DyT; angles ----------------------------------
    {
        int g0 = (p<2) ? p*7 : 14+(p-2)*6;
        int gcount = (p<2) ? 7 : 6;
        float s[6] = {0.f,0.f,0.f,0.f,0.f,0.f};
        for(int gg=0; gg<gcount; gg++){
            int kb = (g0+gg)*4;
            ushort4 tv = *(const ushort4*)&t1s[node*104 + kb];
            float u0=b2f(tv.x), u1=b2f(tv.y), u2=b2f(tv.z), u3=b2f(tv.w);
            #pragma unroll
            for(int j=0;j<6;j++)
                s[j] += u0*s_A2[kb*6+j] + u1*s_A2[(kb+1)*6+j]
                      + u2*s_A2[(kb+2)*6+j] + u3*s_A2[(kb+3)*6+j];
        }
        #pragma unroll
        for(int j=0;j<6;j++){ s[j]+=__shfl_xor(s[j],1,64); s[j]+=__shfl_xor(s[j],2,64); }
        if(p<2){
            size_t o = (size_t)(row0+node)*6 + p*3;
            #pragma unroll
            for(int jj=0;jj<3;jj++){
                int j = p*3+jj;
                float t2v = gelu_f(s[j] + s_a2[j]);
                float uu = tanhf(s_dyt[0]*t2v)*s_dyt[1+j] + s_dyt[8+j];
                out_ang[o+jj] = tanhf(uu);
            }
        }
    }
}

// ---------------------------------------------------------------------------
extern "C" void kernel_launch(void* const* d_in, const int* in_sizes, int n_in,
                              void* d_out, int out_size, void* d_ws, size_t ws_size,
                              hipStream_t stream) {
    const float* x      = (const float*)d_in[0];
    const float* coords = (const float*)d_in[1];
    const int*   ei     = (const int*)d_in[2];
    const float* gamma  = (const float*)d_in[4];
    const float* beta   = (const float*)d_in[5];
    const float* W1     = (const float*)d_in[6];
    const float* b1     = (const float*)d_in[7];
    const float* W2     = (const float*)d_in[8];
    const float* b2     = (const float*)d_in[9];
    const float* W3     = (const float*)d_in[10];
    const float* b3     = (const float*)d_in[11];
    const float* embed  = (const float*)d_in[12];
    const float* W_msg  = (const float*)d_in[13];
    const float* b_msg  = (const float*)d_in[14];
    const float* w_coor = (const float*)d_in[15];
    const float* A1     = (const float*)d_in[16];
    const float* a1v    = (const float*)d_in[17];
    const float* A2     = (const float*)d_in[18];
    const float* a2v    = (const float*)d_in[19];
    const float* dalpha = (const float*)d_in[20];
    const float* dw     = (const float*)d_in[21];
    const float* db     = (const float*)d_in[22];

    // ws layout (44.1 MB peak):
    //  0        : ids   (128 KB)
    //  128K     : stats (2 KB)
    //  256K     : weight planes (512 KB)
    //  1M       : mask  (8 MB)
    //  10M      : h1 fp32 (33.55 MB) ; vbf (8.39 MB) aliases h1 (disjoint lifetime)
    char* ws = (char*)d_ws;
    int*      ids   = (int*)ws;
    float*    stats = (float*)(ws + 131072);
    short*    w1th  = (short*)(ws + 262144);
    short*    w1tl  = w1th + 65536;
    short*    w2th  = w1tl + 65536;
    short*    w2tl  = w2th + 32768;
    short*    wmth  = w2tl + 32768;
    short*    wmtl  = wmth + 16384;
    short*    a1th  = wmtl + 16384;
    short*    a1tl  = a1th + 16384;
    unsigned* mask  = (unsigned*)(ws + (1<<20));
    float*    h1    = (float*)(ws + (size_t)10*1048576);
    unsigned short* vbf = (unsigned short*)(ws + (size_t)10*1048576);

    float* out_ang = (float*)d_out;
    float* out_z   = out_ang + (size_t)NT*OUTC;
    float* out_co  = out_z   + (size_t)NT*DIMd;

    hipMemsetAsync(stats, 0, 2*INC*sizeof(float), stream);
    hipMemsetAsync(mask, 0, (size_t)NT*64*sizeof(unsigned), stream);
    bn_stats_k<<<256, 256, 0, stream>>>(x, stats);
    build_adj_k<<<Ee/256, 256, 0, stream>>>(ei, mask);
    prep_w_k<<<64, 256, 0, stream>>>(W1, W2, W_msg, A1,
        w1th, w1tl, w2th, w2tl, wmth, wmtl, a1th, a1tl);
    gemm1_mfma<<<1024, 256, 0, stream>>>(x, stats, gamma, beta, w1th, w1tl, b1, h1);
    gemm23_mfma<<<512, 256, 0, stream>>>(h1, w2th, w2tl, b2, W3, b3, ids);
    agg_k<<<512, 256, 0, stream>>>(ids, mask, embed, vbf);
    msg2_k<<<512, 256, 0, stream>>>(vbf, wmth, wmtl, b_msg, w_coor,
        a1th, a1tl, a1v, A2, a2v, dalpha, dw, db, coords, out_ang, out_z, out_co);
}